// Round 1
// baseline (575.452 us; speedup 1.0000x reference)
//
#include <hip/hip_runtime.h>

// ---------------------------------------------------------------------------
// MultiHeadAttention: out = softmax_causal((XWq^T)(XWk^T)^T / sqrt(S)) (XWv^T) Wo^T + b
// B=2, S=2048, D=2048, H=16, HD=128.  All compute in bf16 MFMA, fp32 accum.
// ---------------------------------------------------------------------------

typedef __attribute__((ext_vector_type(8))) short short8;
typedef __attribute__((ext_vector_type(4))) float f32x4;

#define SEQ 2048
#define DM  2048
#define NHD 128

__device__ __forceinline__ unsigned short f2bf(float f) {
  unsigned u = __builtin_bit_cast(unsigned, f);
  u += 0x7FFFu + ((u >> 16) & 1u);          // RNE
  return (unsigned short)(u >> 16);
}

__device__ __forceinline__ void gll16(const void* g, void* l) {
  __builtin_amdgcn_global_load_lds((const __attribute__((address_space(1))) void*)g,
                                   (__attribute__((address_space(3))) void*)l, 16, 0, 0);
}

// ---------------- cast fp32 -> bf16, 8 elems/thread ------------------------
__global__ __launch_bounds__(256) void cast_bf16_k(const float* __restrict__ in,
                                                   unsigned short* __restrict__ out,
                                                   int n8) {
  int i = blockIdx.x * 256 + threadIdx.x;
  if (i >= n8) return;
  const f32x4* p = (const f32x4*)in + (size_t)i * 2;
  f32x4 a = p[0], b = p[1];
  short8 o;
  o[0] = (short)f2bf(a[0]); o[1] = (short)f2bf(a[1]);
  o[2] = (short)f2bf(a[2]); o[3] = (short)f2bf(a[3]);
  o[4] = (short)f2bf(b[0]); o[5] = (short)f2bf(b[1]);
  o[6] = (short)f2bf(b[2]); o[7] = (short)f2bf(b[3]);
  *(short8*)(out + (size_t)i * 8) = o;
}

// ---------------- m97-structure 128x128 bf16 GEMM core ---------------------
// Y[m][n] = sum_k A[m][k] * W[n][k]   (both K-major), M=4096 N=2048 K=2048
// block 256 thr = 4 waves (2x2 of 64x64), BK=32, single LDS buffer.

__device__ __forceinline__ void gemm_core(const unsigned short* __restrict__ A,
                                          const unsigned short* __restrict__ W,
                                          unsigned short* la, unsigned short* lb,
                                          f32x4 acc[4][4],
                                          int m0, int n0) {
  const int t = threadIdx.x, w = t >> 6, l = t & 63;
  const int lr = l & 15, kb = l >> 4;
  const int wm = w >> 1, wn = w & 1;
  const int i0 = w * 64 + l, i1 = 256 + w * 64 + l;     // granule ids (16B)
  for (int kt = 0; kt < DM / 32; ++kt) {
    const int k0 = kt * 32;
    gll16(A + (size_t)(m0 + (i0 >> 2)) * DM + k0 + (i0 & 3) * 8, &la[(size_t)w * 512]);
    gll16(A + (size_t)(m0 + (i1 >> 2)) * DM + k0 + (i1 & 3) * 8, &la[(size_t)(4 + w) * 512]);
    gll16(W + (size_t)(n0 + (i0 >> 2)) * DM + k0 + (i0 & 3) * 8, &lb[(size_t)w * 512]);
    gll16(W + (size_t)(n0 + (i1 >> 2)) * DM + k0 + (i1 & 3) * 8, &lb[(size_t)(4 + w) * 512]);
    __syncthreads();   // drains vmcnt, LDS ready
    short8 af[4], bfr[4];
#pragma unroll
    for (int mi = 0; mi < 4; ++mi)
      af[mi] = *(const short8*)&la[(wm * 64 + mi * 16 + lr) * 32 + kb * 8];
#pragma unroll
    for (int ni = 0; ni < 4; ++ni)
      bfr[ni] = *(const short8*)&lb[(wn * 64 + ni * 16 + lr) * 32 + kb * 8];
#pragma unroll
    for (int mi = 0; mi < 4; ++mi)
#pragma unroll
      for (int ni = 0; ni < 4; ++ni)
        acc[mi][ni] = __builtin_amdgcn_mfma_f32_16x16x32_bf16(af[mi], bfr[ni], acc[mi][ni], 0, 0, 0);
    __syncthreads();   // all waves done reading before next stage
  }
}

__global__ __launch_bounds__(256) void gemm_qkv_k(const unsigned short* __restrict__ X,
                                                  const unsigned short* __restrict__ Wq,
                                                  const unsigned short* __restrict__ Wk,
                                                  const unsigned short* __restrict__ Wv,
                                                  unsigned short* __restrict__ Qo,
                                                  unsigned short* __restrict__ Ko,
                                                  unsigned short* __restrict__ Vo) {
  __shared__ unsigned short la[128 * 32];
  __shared__ unsigned short lb[128 * 32];
  const int z = blockIdx.z;
  const unsigned short* W = (z == 0) ? Wq : ((z == 1) ? Wk : Wv);
  unsigned short* Y = (z == 0) ? Qo : ((z == 1) ? Ko : Vo);
  const int m0 = blockIdx.y * 128, n0 = blockIdx.x * 128;
  const int t = threadIdx.x, w = t >> 6, l = t & 63;
  const int lr = l & 15, kb = l >> 4;
  const int wm = w >> 1, wn = w & 1;
  f32x4 acc[4][4] = {};
  gemm_core(X, W, la, lb, acc, m0, n0);
#pragma unroll
  for (int mi = 0; mi < 4; ++mi)
#pragma unroll
    for (int ni = 0; ni < 4; ++ni)
#pragma unroll
      for (int r = 0; r < 4; ++r) {
        int row = m0 + wm * 64 + mi * 16 + kb * 4 + r;
        int col = n0 + wn * 64 + ni * 16 + lr;
        Y[(size_t)row * DM + col] = f2bf(acc[mi][ni][r]);
      }
}

__global__ __launch_bounds__(256) void gemm_o_k(const unsigned short* __restrict__ A,
                                                const unsigned short* __restrict__ W,
                                                const float* __restrict__ bias,
                                                float* __restrict__ Y) {
  __shared__ unsigned short la[128 * 32];
  __shared__ unsigned short lb[128 * 32];
  const int m0 = blockIdx.y * 128, n0 = blockIdx.x * 128;
  const int t = threadIdx.x, w = t >> 6, l = t & 63;
  const int lr = l & 15, kb = l >> 4;
  const int wm = w >> 1, wn = w & 1;
  f32x4 acc[4][4] = {};
  gemm_core(A, W, la, lb, acc, m0, n0);
#pragma unroll
  for (int mi = 0; mi < 4; ++mi)
#pragma unroll
    for (int ni = 0; ni < 4; ++ni)
#pragma unroll
      for (int r = 0; r < 4; ++r) {
        int row = m0 + wm * 64 + mi * 16 + kb * 4 + r;
        int col = n0 + wn * 64 + ni * 16 + lr;
        Y[(size_t)row * DM + col] = acc[mi][ni][r] + bias[col];
      }
}

// ---------------- flash attention, causal, scale 1/sqrt(S) -----------------
// grid (S/64, B*H); 4 waves, each owns 16 q-rows. 64-key tiles.
__global__ __launch_bounds__(256) void attn_k(const unsigned short* __restrict__ Q,
                                              const unsigned short* __restrict__ K,
                                              const unsigned short* __restrict__ V,
                                              unsigned short* __restrict__ O) {
  __shared__ unsigned short Kt[64 * 128];     // [key][d], granule-swizzled per row
  __shared__ unsigned short Vt[128 * 64];     // [d][key] transposed, swizzled
  __shared__ unsigned short Pb[4][16 * 64];   // per-wave P, swizzled
  const int t = threadIdx.x, w = t >> 6, l = t & 63;
  const int lr = l & 15, kb = l >> 4;
  const int bh = blockIdx.y, b = bh >> 4, h = bh & 15;
  const int q0 = blockIdx.x * 64;
  const int qw = q0 + w * 16;
  const float scale = 0.022097086912079608f;  // 1/sqrt(2048)

  short8 qf[4];
  {
    const unsigned short* qp = Q + (size_t)(b * SEQ + qw + lr) * DM + h * NHD + kb * 8;
#pragma unroll
    for (int ks = 0; ks < 4; ++ks) qf[ks] = *(const short8*)(qp + ks * 32);
  }
  f32x4 ctx[8] = {};
  float mrow[4], lrow[4];
#pragma unroll
  for (int r = 0; r < 4; ++r) { mrow[r] = -3.0e4f; lrow[r] = 0.f; }

  const int nkt = blockIdx.x + 1;
  for (int kt = 0; kt < nkt; ++kt) {
    const int kv0 = kt * 64;
    __syncthreads();    // previous iter's LDS reads done
    // K tile: global_load_lds with pre-swizzled source (G21)
#pragma unroll
    for (int c = 0; c < 4; ++c) {
      int idx16 = (c * 4 + w) * 64 + l;
      int row = idx16 >> 4, g = idx16 & 15;
      gll16(K + (size_t)(b * SEQ + kv0 + row) * DM + h * NHD + (g ^ (row & 7)) * 8,
            &Kt[(size_t)(c * 4 + w) * 512]);
    }
    // V tile: reg-staged transpose, swizzled scatter
#pragma unroll
    for (int c = 0; c < 4; ++c) {
      int idx16 = c * 256 + t;
      int vrow = idx16 >> 4, vg = idx16 & 15;
      short8 vv = *(const short8*)(V + (size_t)(b * SEQ + kv0 + vrow) * DM + h * NHD + vg * 8);
#pragma unroll
      for (int j = 0; j < 8; ++j)
        Vt[(vg * 8 + j) * 64 + (vrow ^ (j * 8))] = (unsigned short)vv[j];
    }
    __syncthreads();
    // QK^T : 16 MFMAs -> s[ct] holds scores[q=kb*4+r][key=ct*16+lr]
    f32x4 s[4];
#pragma unroll
    for (int ct = 0; ct < 4; ++ct) {
      s[ct] = (f32x4){0.f, 0.f, 0.f, 0.f};
#pragma unroll
      for (int ks = 0; ks < 4; ++ks) {
        int krow = ct * 16 + lr;
        short8 bf = *(const short8*)&Kt[krow * 128 + ((ks * 4 + kb) ^ (krow & 7)) * 8];
        s[ct] = __builtin_amdgcn_mfma_f32_16x16x32_bf16(qf[ks], bf, s[ct], 0, 0, 0);
      }
    }
    // online softmax (16-lane shfl reduce; rows are kb*4+r)
    float pe[4][4];
#pragma unroll
    for (int r = 0; r < 4; ++r) {
      const int qi = qw + kb * 4 + r;
      float mx = -3.0e4f;
#pragma unroll
      for (int ct = 0; ct < 4; ++ct) {
        float v = s[ct][r] * scale;
        if (kv0 + ct * 16 + lr > qi) v = -3.0e4f;   // causal mask
        s[ct][r] = v;
        mx = fmaxf(mx, v);
      }
      mx = fmaxf(mx, __shfl_xor(mx, 1));
      mx = fmaxf(mx, __shfl_xor(mx, 2));
      mx = fmaxf(mx, __shfl_xor(mx, 4));
      mx = fmaxf(mx, __shfl_xor(mx, 8));
      float mnew = fmaxf(mrow[r], mx);
      float alpha = __expf(mrow[r] - mnew);
      mrow[r] = mnew;
      float rs = 0.f;
#pragma unroll
      for (int ct = 0; ct < 4; ++ct) {
        float e = __expf(s[ct][r] - mnew);
        pe[ct][r] = e;
        rs += e;
      }
      rs += __shfl_xor(rs, 1);
      rs += __shfl_xor(rs, 2);
      rs += __shfl_xor(rs, 4);
      rs += __shfl_xor(rs, 8);
      lrow[r] = lrow[r] * alpha + rs;
#pragma unroll
      for (int c = 0; c < 8; ++c) ctx[c][r] *= alpha;
    }
    // P -> per-wave LDS (transpose to A-frag layout)
#pragma unroll
    for (int ct = 0; ct < 4; ++ct)
#pragma unroll
      for (int r = 0; r < 4; ++r) {
        int prow = kb * 4 + r, pcol = ct * 16 + lr;
        Pb[w][prow * 64 + (pcol ^ ((prow & 7) * 8))] = f2bf(pe[ct][r]);
      }
    // PV : ctx[16 x 128] += P[16 x 64] * V[64 x 128]
    short8 pa[2];
#pragma unroll
    for (int ks = 0; ks < 2; ++ks)
      pa[ks] = *(const short8*)&Pb[w][lr * 64 + ((ks * 4 + kb) ^ (lr & 7)) * 8];
#pragma unroll
    for (int c = 0; c < 8; ++c) {
      int vrow = c * 16 + lr;
#pragma unroll
      for (int ks = 0; ks < 2; ++ks) {
        short8 vb = *(const short8*)&Vt[vrow * 64 + ((ks * 4 + kb) ^ (vrow & 7)) * 8];
        ctx[c] = __builtin_amdgcn_mfma_f32_16x16x32_bf16(pa[ks], vb, ctx[c], 0, 0, 0);
      }
    }
  }
  // epilogue: ctx /= l, write bf16
#pragma unroll
  for (int r = 0; r < 4; ++r) {
    float inv = 1.f / lrow[r];
    size_t rowoff = (size_t)(b * SEQ + qw + kb * 4 + r) * DM + h * NHD;
#pragma unroll
    for (int c = 0; c < 8; ++c)
      O[rowoff + c * 16 + lr] = f2bf(ctx[c][r] * inv);
  }
}

// ---------------------------------------------------------------------------
extern "C" void kernel_launch(void* const* d_in, const int* in_sizes, int n_in,
                              void* d_out, int out_size, void* d_ws, size_t ws_size,
                              hipStream_t stream) {
  const float* X  = (const float*)d_in[0];
  const float* Wq = (const float*)d_in[1];
  const float* Wk = (const float*)d_in[2];
  const float* Wv = (const float*)d_in[3];
  const float* Wo = (const float*)d_in[4];
  const float* bo = (const float*)d_in[5];
  float* out = (float*)d_out;

  unsigned short* ws = (unsigned short*)d_ws;
  // workspace layout (ushort elems)
  unsigned short* Xb  = ws;                    // 2*2048*2048 = 8388608
  unsigned short* Wqb = ws + 8388608;          // 4194304
  unsigned short* Wkb = ws + 12582912;
  unsigned short* Wvb = ws + 16777216;
  unsigned short* Wob = ws + 20971520;
  unsigned short* Qb  = ws + 25165824;         // 8388608 each
  unsigned short* Kb  = ws + 33554432;
  unsigned short* Vb  = ws + 41943040;
  unsigned short* Cb  = ws + 50331648;         // end: 58720256 ushorts = 112 MiB

  cast_bf16_k<<<4096, 256, 0, stream>>>(X, Xb, 1048576);
  cast_bf16_k<<<2048, 256, 0, stream>>>(Wq, Wqb, 524288);
  cast_bf16_k<<<2048, 256, 0, stream>>>(Wk, Wkb, 524288);
  cast_bf16_k<<<2048, 256, 0, stream>>>(Wv, Wvb, 524288);
  cast_bf16_k<<<2048, 256, 0, stream>>>(Wo, Wob, 524288);

  gemm_qkv_k<<<dim3(16, 32, 3), 256, 0, stream>>>(Xb, Wqb, Wkb, Wvb, Qb, Kb, Vb);
  attn_k<<<dim3(32, 32), 256, 0, stream>>>(Qb, Kb, Vb, Cb);
  gemm_o_k<<<dim3(16, 32), 256, 0, stream>>>(Cb, Wob, bo, out);
}

// Round 2
// 389.958 us; speedup vs baseline: 1.4757x; 1.4757x over previous
//
#include <hip/hip_runtime.h>

// ---------------------------------------------------------------------------
// MultiHeadAttention: out = softmax_causal((XWq^T)(XWk^T)^T / sqrt(S)) (XWv^T) Wo^T + b
// B=2, S=2048, D=2048, H=16, HD=128.  All compute in bf16 MFMA, fp32 accum.
// ---------------------------------------------------------------------------

typedef __attribute__((ext_vector_type(8))) short short8;
typedef __attribute__((ext_vector_type(4))) float f32x4;

#define SEQ 2048
#define DM  2048
#define NHD 128

__device__ __forceinline__ unsigned short f2bf(float f) {
  unsigned u = __builtin_bit_cast(unsigned, f);
  u += 0x7FFFu + ((u >> 16) & 1u);          // RNE
  return (unsigned short)(u >> 16);
}

__device__ __forceinline__ void gll16(const void* g, void* l) {
  __builtin_amdgcn_global_load_lds((const __attribute__((address_space(1))) void*)g,
                                   (__attribute__((address_space(3))) void*)l, 16, 0, 0);
}

// ---------------- cast fp32 -> bf16, 8 elems/thread ------------------------
__global__ __launch_bounds__(256) void cast_bf16_k(const float* __restrict__ in,
                                                   unsigned short* __restrict__ out,
                                                   int n8) {
  int i = blockIdx.x * 256 + threadIdx.x;
  if (i >= n8) return;
  const f32x4* p = (const f32x4*)in + (size_t)i * 2;
  f32x4 a = p[0], b = p[1];
  short8 o;
  o[0] = (short)f2bf(a[0]); o[1] = (short)f2bf(a[1]);
  o[2] = (short)f2bf(a[2]); o[3] = (short)f2bf(a[3]);
  o[4] = (short)f2bf(b[0]); o[5] = (short)f2bf(b[1]);
  o[6] = (short)f2bf(b[2]); o[7] = (short)f2bf(b[3]);
  *(short8*)(out + (size_t)i * 8) = o;
}

// ---------------- m97-structure 128x128 bf16 GEMM core ---------------------
// acc[mi][ni] = sum_k A[m][k] * W[n][k]  (both K-major), BK=32, 4 waves.
__device__ __forceinline__ void gemm_core(const unsigned short* __restrict__ A,
                                          const unsigned short* __restrict__ W,
                                          unsigned short* la, unsigned short* lb,
                                          f32x4 acc[4][4],
                                          int m0, int n0) {
  const int t = threadIdx.x, w = t >> 6, l = t & 63;
  const int lr = l & 15, kb = l >> 4;
  const int wm = w >> 1, wn = w & 1;
  const int i0 = w * 64 + l, i1 = 256 + w * 64 + l;     // granule ids (16B)
  for (int kt = 0; kt < DM / 32; ++kt) {
    const int k0 = kt * 32;
    gll16(A + (size_t)(m0 + (i0 >> 2)) * DM + k0 + (i0 & 3) * 8, &la[(size_t)w * 512]);
    gll16(A + (size_t)(m0 + (i1 >> 2)) * DM + k0 + (i1 & 3) * 8, &la[(size_t)(4 + w) * 512]);
    gll16(W + (size_t)(n0 + (i0 >> 2)) * DM + k0 + (i0 & 3) * 8, &lb[(size_t)w * 512]);
    gll16(W + (size_t)(n0 + (i1 >> 2)) * DM + k0 + (i1 & 3) * 8, &lb[(size_t)(4 + w) * 512]);
    __syncthreads();
    short8 af[4], bfr[4];
#pragma unroll
    for (int mi = 0; mi < 4; ++mi)
      af[mi] = *(const short8*)&la[(wm * 64 + mi * 16 + lr) * 32 + kb * 8];
#pragma unroll
    for (int ni = 0; ni < 4; ++ni)
      bfr[ni] = *(const short8*)&lb[(wn * 64 + ni * 16 + lr) * 32 + kb * 8];
#pragma unroll
    for (int mi = 0; mi < 4; ++mi)
#pragma unroll
      for (int ni = 0; ni < 4; ++ni)
        acc[mi][ni] = __builtin_amdgcn_mfma_f32_16x16x32_bf16(af[mi], bfr[ni], acc[mi][ni], 0, 0, 0);
    __syncthreads();
  }
}

// Q and K projections: Y[s][n] = X[s][:] . W[n][:]
__global__ __launch_bounds__(256) void gemm_qk_k(const unsigned short* __restrict__ X,
                                                 const unsigned short* __restrict__ Wq,
                                                 const unsigned short* __restrict__ Wk,
                                                 unsigned short* __restrict__ Qo,
                                                 unsigned short* __restrict__ Ko) {
  __shared__ unsigned short la[128 * 32];
  __shared__ unsigned short lb[128 * 32];
  const int z = blockIdx.z;
  const unsigned short* W = z ? Wk : Wq;
  unsigned short* Y = z ? Ko : Qo;
  const int m0 = blockIdx.y * 128, n0 = blockIdx.x * 128;
  const int t = threadIdx.x, w = t >> 6, l = t & 63;
  const int lr = l & 15, kb = l >> 4;
  const int wm = w >> 1, wn = w & 1;
  f32x4 acc[4][4] = {};
  gemm_core(X, W, la, lb, acc, m0, n0);
#pragma unroll
  for (int mi = 0; mi < 4; ++mi)
#pragma unroll
    for (int ni = 0; ni < 4; ++ni)
#pragma unroll
      for (int r = 0; r < 4; ++r) {
        int row = m0 + wm * 64 + mi * 16 + kb * 4 + r;
        int col = n0 + wn * 64 + ni * 16 + lr;
        Y[(size_t)row * DM + col] = f2bf(acc[mi][ni][r]);
      }
}

// V projection writing transposed: Vt[(b*16+h)*128+d][s] = X[b,s,:] . Wv[h*128+d,:]
// Computed as GEMM with A = Wv (rows i = h*128+d), B = X (rows j = b*2048+s).
__global__ __launch_bounds__(256) void gemm_vt_k(const unsigned short* __restrict__ Wv,
                                                 const unsigned short* __restrict__ X,
                                                 unsigned short* __restrict__ Vt) {
  __shared__ unsigned short la[128 * 32];
  __shared__ unsigned short lb[128 * 32];
  const int m0 = blockIdx.y * 128, n0 = blockIdx.x * 128;
  const int t = threadIdx.x, w = t >> 6, l = t & 63;
  const int lr = l & 15, kb = l >> 4;
  const int wm = w >> 1, wn = w & 1;
  f32x4 acc[4][4] = {};
  gemm_core(Wv, X, la, lb, acc, m0, n0);
#pragma unroll
  for (int mi = 0; mi < 4; ++mi)
#pragma unroll
    for (int ni = 0; ni < 4; ++ni)
#pragma unroll
      for (int r = 0; r < 4; ++r) {
        int i = m0 + wm * 64 + mi * 16 + kb * 4 + r;   // h*128+d
        int j = n0 + wn * 64 + ni * 16 + lr;           // b*2048+s
        Vt[((size_t)(j >> 11) * 2048 + i) * 2048 + (j & 2047)] = f2bf(acc[mi][ni][r]);
      }
}

__global__ __launch_bounds__(256) void gemm_o_k(const unsigned short* __restrict__ A,
                                                const unsigned short* __restrict__ W,
                                                const float* __restrict__ bias,
                                                float* __restrict__ Y) {
  __shared__ unsigned short la[128 * 32];
  __shared__ unsigned short lb[128 * 32];
  const int m0 = blockIdx.y * 128, n0 = blockIdx.x * 128;
  const int t = threadIdx.x, w = t >> 6, l = t & 63;
  const int lr = l & 15, kb = l >> 4;
  const int wm = w >> 1, wn = w & 1;
  f32x4 acc[4][4] = {};
  gemm_core(A, W, la, lb, acc, m0, n0);
#pragma unroll
  for (int mi = 0; mi < 4; ++mi)
#pragma unroll
    for (int ni = 0; ni < 4; ++ni)
#pragma unroll
      for (int r = 0; r < 4; ++r) {
        int row = m0 + wm * 64 + mi * 16 + kb * 4 + r;
        int col = n0 + wn * 64 + ni * 16 + lr;
        Y[(size_t)row * DM + col] = acc[mi][ni][r] + bias[col];
      }
}

// ---------------- flash attention, causal, scale 1/sqrt(S) -----------------
// grid (16, 32): block handles q-tiles {x, 31-x} -> exactly 33 k-tiles each.
// K tile [64 key][128 d] and Vt tile [128 d][64 key] staged via global_load_lds
// with pre-swizzled source granules; double-buffered 2-phase pipeline.
__device__ __forceinline__ void stage_tiles(const unsigned short* __restrict__ Kh,
                                            const unsigned short* __restrict__ Vh,
                                            unsigned short* KL, unsigned short* VL,
                                            int kv0, int t) {
#pragma unroll
  for (int c = 0; c < 4; ++c) {          // K: 1024 granules, slot S = row*16 + (g^(row&7))
    int S = c * 256 + t;
    int row = S >> 4, g = (S & 15) ^ (row & 7);
    gll16(Kh + (size_t)(kv0 + row) * DM + g * 8, KL + (size_t)S * 8);
  }
#pragma unroll
  for (int c = 0; c < 4; ++c) {          // V: 1024 granules, slot S = d*8 + (g^(d&7))
    int S = c * 256 + t;
    int d = S >> 3, g = (S & 7) ^ (d & 7);
    gll16(Vh + (size_t)d * SEQ + kv0 + g * 8, VL + (size_t)S * 8);
  }
}

__global__ __launch_bounds__(256) void attn_k(const unsigned short* __restrict__ Q,
                                              const unsigned short* __restrict__ K,
                                              const unsigned short* __restrict__ Vt,
                                              unsigned short* __restrict__ O) {
  __shared__ unsigned short KL[2][64 * 128];
  __shared__ unsigned short VL[2][128 * 64];
  __shared__ unsigned short Pb[4][16 * 64];
  const int t = threadIdx.x, w = t >> 6, l = t & 63;
  const int lr = l & 15, kb = l >> 4;
  const int bh = blockIdx.y, b = bh >> 4, h = bh & 15;
  const unsigned short* Kh = K + (size_t)b * SEQ * DM + h * NHD;
  const unsigned short* Vh = Vt + (size_t)bh * NHD * SEQ;
  const float scale = 0.022097086912079608f;  // 1/sqrt(2048)

#pragma unroll 1
  for (int phase = 0; phase < 2; ++phase) {
    const int xq = phase ? (31 - (int)blockIdx.x) : (int)blockIdx.x;
    const int q0 = xq * 64;
    const int qw = q0 + w * 16;
    const int nkt = xq + 1;

    short8 qf[4];
    {
      const unsigned short* qp = Q + (size_t)(b * SEQ + qw + lr) * DM + h * NHD + kb * 8;
#pragma unroll
      for (int ks = 0; ks < 4; ++ks) qf[ks] = *(const short8*)(qp + ks * 32);
    }
    f32x4 ctx[8] = {};
    float mrow[4], lrow[4];
#pragma unroll
    for (int r = 0; r < 4; ++r) { mrow[r] = -3.0e4f; lrow[r] = 0.f; }

    stage_tiles(Kh, Vh, KL[0], VL[0], 0, t);
    __syncthreads();

    int cbuf = 0;
#pragma unroll 1
    for (int kt = 0; kt < nkt; ++kt) {
      const int kv0 = kt * 64;
      if (kt + 1 < nkt) stage_tiles(Kh, Vh, KL[cbuf ^ 1], VL[cbuf ^ 1], kv0 + 64, t);
      const unsigned short* Kc = KL[cbuf];
      const unsigned short* Vc = VL[cbuf];
      // QK^T: s[ct][r] = scores[q=kb*4+r][key=ct*16+lr]
      f32x4 s[4];
#pragma unroll
      for (int ct = 0; ct < 4; ++ct) {
        s[ct] = (f32x4){0.f, 0.f, 0.f, 0.f};
        int krow = ct * 16 + lr;
#pragma unroll
        for (int ks = 0; ks < 4; ++ks) {
          short8 bf = *(const short8*)&Kc[krow * 128 + (((ks * 4 + kb) ^ (krow & 7)) * 8)];
          s[ct] = __builtin_amdgcn_mfma_f32_16x16x32_bf16(qf[ks], bf, s[ct], 0, 0, 0);
        }
      }
      const bool needmask = (kv0 + 63 > qw);
      float pe[4][4];
#pragma unroll
      for (int r = 0; r < 4; ++r) {
        const int qi = qw + kb * 4 + r;
        float mx = -3.0e4f;
#pragma unroll
        for (int ct = 0; ct < 4; ++ct) {
          float v = s[ct][r] * scale;
          if (needmask && (kv0 + ct * 16 + lr > qi)) v = -3.0e4f;
          s[ct][r] = v;
          mx = fmaxf(mx, v);
        }
        mx = fmaxf(mx, __shfl_xor(mx, 1));
        mx = fmaxf(mx, __shfl_xor(mx, 2));
        mx = fmaxf(mx, __shfl_xor(mx, 4));
        mx = fmaxf(mx, __shfl_xor(mx, 8));
        if (mx > mrow[r] + 8.f) {          // defer-max (T13)
          float alpha = __expf(mrow[r] - mx);
          mrow[r] = mx;
          lrow[r] *= alpha;
#pragma unroll
          for (int cc = 0; cc < 8; ++cc) ctx[cc][r] *= alpha;
        }
        float rs = 0.f;
#pragma unroll
        for (int ct = 0; ct < 4; ++ct) {
          float e = __expf(s[ct][r] - mrow[r]);
          pe[ct][r] = e;
          rs += e;
        }
        rs += __shfl_xor(rs, 1);
        rs += __shfl_xor(rs, 2);
        rs += __shfl_xor(rs, 4);
        rs += __shfl_xor(rs, 8);
        lrow[r] += rs;
      }
      // P -> per-wave LDS (swizzled)
#pragma unroll
      for (int ct = 0; ct < 4; ++ct)
#pragma unroll
        for (int r = 0; r < 4; ++r) {
          int prow = kb * 4 + r, pcol = ct * 16 + lr;
          Pb[w][prow * 64 + (pcol ^ ((prow & 7) * 8))] = f2bf(pe[ct][r]);
        }
      // PV: ctx[16 x 128] += P[16 x 64] * V[64 x 128]
      short8 pa[2];
#pragma unroll
      for (int ks = 0; ks < 2; ++ks)
        pa[ks] = *(const short8*)&Pb[w][lr * 64 + (((ks * 4 + kb) ^ (lr & 7)) * 8)];
#pragma unroll
      for (int cc = 0; cc < 8; ++cc) {
        int vrow = cc * 16 + lr;
#pragma unroll
        for (int ks = 0; ks < 2; ++ks) {
          short8 vb = *(const short8*)&Vc[vrow * 64 + (((ks * 4 + kb) ^ (vrow & 7)) * 8)];
          ctx[cc] = __builtin_amdgcn_mfma_f32_16x16x32_bf16(pa[ks], vb, ctx[cc], 0, 0, 0);
        }
      }
      __syncthreads();   // drains vmcnt(0): next tile staged, cur buffers free
      cbuf ^= 1;
    }
    // epilogue: ctx /= l, write bf16
#pragma unroll
    for (int r = 0; r < 4; ++r) {
      float inv = 1.f / lrow[r];
      size_t rowoff = (size_t)(b * SEQ + qw + kb * 4 + r) * DM + h * NHD;
#pragma unroll
      for (int cc = 0; cc < 8; ++cc)
        O[rowoff + cc * 16 + lr] = f2bf(ctx[cc][r] * inv);
    }
  }
}

// ---------------------------------------------------------------------------
extern "C" void kernel_launch(void* const* d_in, const int* in_sizes, int n_in,
                              void* d_out, int out_size, void* d_ws, size_t ws_size,
                              hipStream_t stream) {
  const float* X  = (const float*)d_in[0];
  const float* Wq = (const float*)d_in[1];
  const float* Wk = (const float*)d_in[2];
  const float* Wv = (const float*)d_in[3];
  const float* Wo = (const float*)d_in[4];
  const float* bo = (const float*)d_in[5];
  float* out = (float*)d_out;

  unsigned short* ws = (unsigned short*)d_ws;
  unsigned short* Xb  = ws;                    // 8388608
  unsigned short* Wqb = ws + 8388608;          // 4194304
  unsigned short* Wkb = ws + 12582912;
  unsigned short* Wvb = ws + 16777216;
  unsigned short* Wob = ws + 20971520;
  unsigned short* Qb  = ws + 25165824;         // 8388608
  unsigned short* Kb  = ws + 33554432;
  unsigned short* Vtb = ws + 41943040;         // Vt[(b*16+h)*128+d][s]
  unsigned short* Cb  = ws + 50331648;

  cast_bf16_k<<<4096, 256, 0, stream>>>(X, Xb, 1048576);
  cast_bf16_k<<<2048, 256, 0, stream>>>(Wq, Wqb, 524288);
  cast_bf16_k<<<2048, 256, 0, stream>>>(Wk, Wkb, 524288);
  cast_bf16_k<<<2048, 256, 0, stream>>>(Wv, Wvb, 524288);
  cast_bf16_k<<<2048, 256, 0, stream>>>(Wo, Wob, 524288);

  gemm_qk_k<<<dim3(16, 32, 2), 256, 0, stream>>>(Xb, Wqb, Wkb, Qb, Kb);
  gemm_vt_k<<<dim3(32, 16), 256, 0, stream>>>(Wvb, Xb, Vtb);
  attn_k<<<dim3(16, 32), 256, 0, stream>>>(Qb, Kb, Vtb, Cb);
  gemm_o_k<<<dim3(16, 32), 256, 0, stream>>>(Cb, Wob, bo, out);
}

// Round 4
// 370.557 us; speedup vs baseline: 1.5529x; 1.0524x over previous
//
#include <hip/hip_runtime.h>

// ---------------------------------------------------------------------------
// MultiHeadAttention: out = softmax_causal((XWq^T)(XWk^T)^T / sqrt(S)) (XWv^T) Wo^T + b
// B=2, S=2048, D=2048, H=16, HD=128.  All compute in bf16 MFMA, fp32 accum.
// Softmax runs in exp2 domain: Wq is pre-scaled by (1/sqrt(S))*log2(e).
// ---------------------------------------------------------------------------

typedef __attribute__((ext_vector_type(8))) short short8;
typedef __attribute__((ext_vector_type(4))) float f32x4;

#define SEQ 2048
#define DM  2048
#define NHD 128
#define QSCALE (0.022097086912079608f * 1.4426950408889634f)  // 1/sqrt(2048) * log2(e)

// raw v_exp_f32 (2^x) — avoids glibc __exp2f macro collision
#define EXP2F(x) __builtin_amdgcn_exp2f(x)

__device__ __forceinline__ unsigned short f2bf(float f) {
  unsigned u = __builtin_bit_cast(unsigned, f);
  u += 0x7FFFu + ((u >> 16) & 1u);          // RNE
  return (unsigned short)(u >> 16);
}

__device__ __forceinline__ void gll16(const void* g, void* l) {
  __builtin_amdgcn_global_load_lds((const __attribute__((address_space(1))) void*)g,
                                   (__attribute__((address_space(3))) void*)l, 16, 0, 0);
}

// ---------------- cast fp32 -> bf16, 8 elems/thread ------------------------
__global__ __launch_bounds__(256) void cast_bf16_k(const float* __restrict__ in,
                                                   unsigned short* __restrict__ out,
                                                   int n8) {
  int i = blockIdx.x * 256 + threadIdx.x;
  if (i >= n8) return;
  const f32x4* p = (const f32x4*)in + (size_t)i * 2;
  f32x4 a = p[0], b = p[1];
  short8 o;
  o[0] = (short)f2bf(a[0]); o[1] = (short)f2bf(a[1]);
  o[2] = (short)f2bf(a[2]); o[3] = (short)f2bf(a[3]);
  o[4] = (short)f2bf(b[0]); o[5] = (short)f2bf(b[1]);
  o[6] = (short)f2bf(b[2]); o[7] = (short)f2bf(b[3]);
  *(short8*)(out + (size_t)i * 8) = o;
}

// fused cast of the 4 weight matrices; Wq gets QSCALE folded in.
__global__ __launch_bounds__(256) void cast_w4_k(const float* __restrict__ Wq,
                                                 const float* __restrict__ Wk,
                                                 const float* __restrict__ Wv,
                                                 const float* __restrict__ Wo,
                                                 unsigned short* __restrict__ Wqb,
                                                 unsigned short* __restrict__ Wkb,
                                                 unsigned short* __restrict__ Wvb,
                                                 unsigned short* __restrict__ Wob) {
  int i = blockIdx.x * 256 + threadIdx.x;     // 0 .. 4*524288-1
  int r = i >> 19, j = i & 524287;
  const float* src = (r == 0) ? Wq : (r == 1) ? Wk : (r == 2) ? Wv : Wo;
  unsigned short* dst = (r == 0) ? Wqb : (r == 1) ? Wkb : (r == 2) ? Wvb : Wob;
  float sc = (r == 0) ? QSCALE : 1.0f;
  const f32x4* p = (const f32x4*)src + (size_t)j * 2;
  f32x4 a = p[0], b = p[1];
  short8 o;
  o[0] = (short)f2bf(a[0] * sc); o[1] = (short)f2bf(a[1] * sc);
  o[2] = (short)f2bf(a[2] * sc); o[3] = (short)f2bf(a[3] * sc);
  o[4] = (short)f2bf(b[0] * sc); o[5] = (short)f2bf(b[1] * sc);
  o[6] = (short)f2bf(b[2] * sc); o[7] = (short)f2bf(b[3] * sc);
  *(short8*)(dst + (size_t)j * 8) = o;
}

// ---------------- m97-structure 128x128 bf16 GEMM core ---------------------
__device__ __forceinline__ void gemm_core(const unsigned short* __restrict__ A,
                                          const unsigned short* __restrict__ W,
                                          unsigned short* la, unsigned short* lb,
                                          f32x4 acc[4][4],
                                          int m0, int n0) {
  const int t = threadIdx.x, w = t >> 6, l = t & 63;
  const int lr = l & 15, kb = l >> 4;
  const int wm = w >> 1, wn = w & 1;
  const int i0 = w * 64 + l, i1 = 256 + w * 64 + l;     // granule ids (16B)
  for (int kt = 0; kt < DM / 32; ++kt) {
    const int k0 = kt * 32;
    gll16(A + (size_t)(m0 + (i0 >> 2)) * DM + k0 + (i0 & 3) * 8, &la[(size_t)w * 512]);
    gll16(A + (size_t)(m0 + (i1 >> 2)) * DM + k0 + (i1 & 3) * 8, &la[(size_t)(4 + w) * 512]);
    gll16(W + (size_t)(n0 + (i0 >> 2)) * DM + k0 + (i0 & 3) * 8, &lb[(size_t)w * 512]);
    gll16(W + (size_t)(n0 + (i1 >> 2)) * DM + k0 + (i1 & 3) * 8, &lb[(size_t)(4 + w) * 512]);
    __syncthreads();
    short8 af[4], bfr[4];
#pragma unroll
    for (int mi = 0; mi < 4; ++mi)
      af[mi] = *(const short8*)&la[(wm * 64 + mi * 16 + lr) * 32 + kb * 8];
#pragma unroll
    for (int ni = 0; ni < 4; ++ni)
      bfr[ni] = *(const short8*)&lb[(wn * 64 + ni * 16 + lr) * 32 + kb * 8];
#pragma unroll
    for (int mi = 0; mi < 4; ++mi)
#pragma unroll
      for (int ni = 0; ni < 4; ++ni)
        acc[mi][ni] = __builtin_amdgcn_mfma_f32_16x16x32_bf16(af[mi], bfr[ni], acc[mi][ni], 0, 0, 0);
    __syncthreads();
  }
}

// Q and K projections
__global__ __launch_bounds__(256) void gemm_qk_k(const unsigned short* __restrict__ X,
                                                 const unsigned short* __restrict__ Wq,
                                                 const unsigned short* __restrict__ Wk,
                                                 unsigned short* __restrict__ Qo,
                                                 unsigned short* __restrict__ Ko) {
  __shared__ unsigned short la[128 * 32];
  __shared__ unsigned short lb[128 * 32];
  const int z = blockIdx.z;
  const unsigned short* W = z ? Wk : Wq;
  unsigned short* Y = z ? Ko : Qo;
  const int m0 = blockIdx.y * 128, n0 = blockIdx.x * 128;
  const int t = threadIdx.x, w = t >> 6, l = t & 63;
  const int lr = l & 15, kb = l >> 4;
  const int wm = w >> 1, wn = w & 1;
  f32x4 acc[4][4] = {};
  gemm_core(X, W, la, lb, acc, m0, n0);
#pragma unroll
  for (int mi = 0; mi < 4; ++mi)
#pragma unroll
    for (int ni = 0; ni < 4; ++ni)
#pragma unroll
      for (int r = 0; r < 4; ++r) {
        int row = m0 + wm * 64 + mi * 16 + kb * 4 + r;
        int col = n0 + wn * 64 + ni * 16 + lr;
        Y[(size_t)row * DM + col] = f2bf(acc[mi][ni][r]);
      }
}

// V projection written transposed: Vt[(b*16+h)*128+d][s]
__global__ __launch_bounds__(256) void gemm_vt_k(const unsigned short* __restrict__ Wv,
                                                 const unsigned short* __restrict__ X,
                                                 unsigned short* __restrict__ Vt) {
  __shared__ unsigned short la[128 * 32];
  __shared__ unsigned short lb[128 * 32];
  const int m0 = blockIdx.y * 128, n0 = blockIdx.x * 128;
  const int t = threadIdx.x, w = t >> 6, l = t & 63;
  const int lr = l & 15, kb = l >> 4;
  const int wm = w >> 1, wn = w & 1;
  f32x4 acc[4][4] = {};
  gemm_core(Wv, X, la, lb, acc, m0, n0);
#pragma unroll
  for (int mi = 0; mi < 4; ++mi)
#pragma unroll
    for (int ni = 0; ni < 4; ++ni)
#pragma unroll
      for (int r = 0; r < 4; ++r) {
        int i = m0 + wm * 64 + mi * 16 + kb * 4 + r;   // h*128+d
        int j = n0 + wn * 64 + ni * 16 + lr;           // b*2048+s
        Vt[((size_t)(j >> 11) * 2048 + i) * 2048 + (j & 2047)] = f2bf(acc[mi][ni][r]);
      }
}

__global__ __launch_bounds__(256) void gemm_o_k(const unsigned short* __restrict__ A,
                                                const unsigned short* __restrict__ W,
                                                const float* __restrict__ bias,
                                                float* __restrict__ Y) {
  __shared__ unsigned short la[128 * 32];
  __shared__ unsigned short lb[128 * 32];
  const int m0 = blockIdx.y * 128, n0 = blockIdx.x * 128;
  const int t = threadIdx.x, w = t >> 6, l = t & 63;
  const int lr = l & 15, kb = l >> 4;
  const int wm = w >> 1, wn = w & 1;
  f32x4 acc[4][4] = {};
  gemm_core(A, W, la, lb, acc, m0, n0);
#pragma unroll
  for (int mi = 0; mi < 4; ++mi)
#pragma unroll
    for (int ni = 0; ni < 4; ++ni)
#pragma unroll
      for (int r = 0; r < 4; ++r) {
        int row = m0 + wm * 64 + mi * 16 + kb * 4 + r;
        int col = n0 + wn * 64 + ni * 16 + lr;
        Y[(size_t)row * DM + col] = acc[mi][ni][r] + bias[col];
      }
}

// ---------------- flash attention, causal, exp2-domain softmax -------------
// 1-D grid 512, XCD-swizzled: xcd=id&7 hosts bh in [xcd*4, xcd*4+4) so each
// XCD's L2 holds 4 bh x 1MB of K/V. Block does q-tiles {x, 31-x}: 33 k-tiles.
__device__ __forceinline__ void stage_tiles(const unsigned short* __restrict__ Kh,
                                            const unsigned short* __restrict__ Vh,
                                            unsigned short* KL, unsigned short* VL,
                                            int kv0, int t) {
#pragma unroll
  for (int c = 0; c < 4; ++c) {          // K: slot S = row*16 + (g^(row&7))
    int S = c * 256 + t;
    int row = S >> 4, g = (S & 15) ^ (row & 7);
    gll16(Kh + (size_t)(kv0 + row) * DM + g * 8, KL + (size_t)S * 8);
  }
#pragma unroll
  for (int c = 0; c < 4; ++c) {          // V: slot S = d*8 + (g^(d&7))
    int S = c * 256 + t;
    int d = S >> 3, g = (S & 7) ^ (d & 7);
    gll16(Vh + (size_t)d * SEQ + kv0 + g * 8, VL + (size_t)S * 8);
  }
}

__global__ __launch_bounds__(256) void attn_k(const unsigned short* __restrict__ Q,
                                              const unsigned short* __restrict__ K,
                                              const unsigned short* __restrict__ Vt,
                                              unsigned short* __restrict__ O) {
  __shared__ unsigned short KL[2][64 * 128];
  __shared__ unsigned short VL[2][128 * 64];
  __shared__ unsigned short Pb[4][16 * 64];
  const int t = threadIdx.x, w = t >> 6, l = t & 63;
  const int lr = l & 15, kb = l >> 4;
  const int id = blockIdx.x;
  const int xcd = id & 7, slot = id >> 3;
  const int bh = xcd * 4 + (slot & 3);          // T1: bh pinned to one XCD
  const int xpair = slot >> 2;                  // 0..15
  const int b = bh >> 4, h = bh & 15;
  const unsigned short* Kh = K + (size_t)b * SEQ * DM + h * NHD;
  const unsigned short* Vh = Vt + (size_t)bh * NHD * SEQ;

#pragma unroll 1
  for (int phase = 0; phase < 2; ++phase) {
    const int xq = phase ? (31 - xpair) : xpair;
    const int q0 = xq * 64;
    const int qw = q0 + w * 16;
    const int nkt = xq + 1;

    short8 qf[4];
    {
      const unsigned short* qp = Q + (size_t)(b * SEQ + qw + lr) * DM + h * NHD + kb * 8;
#pragma unroll
      for (int ks = 0; ks < 4; ++ks) qf[ks] = *(const short8*)(qp + ks * 32);
    }
    f32x4 ctx[8] = {};
    float mrow[4], lrow[4];
#pragma unroll
    for (int r = 0; r < 4; ++r) { mrow[r] = -3.0e4f; lrow[r] = 0.f; }

    stage_tiles(Kh, Vh, KL[0], VL[0], 0, t);
    __syncthreads();

    int cbuf = 0;
#pragma unroll 1
    for (int kt = 0; kt < nkt; ++kt) {
      const int kv0 = kt * 64;
      if (kt + 1 < nkt) stage_tiles(Kh, Vh, KL[cbuf ^ 1], VL[cbuf ^ 1], kv0 + 64, t);
      const unsigned short* Kc = KL[cbuf];
      const unsigned short* Vc = VL[cbuf];
      // QK^T: s[ct][r] = log2-domain scores[q=kb*4+r][key=ct*16+lr]
      f32x4 s[4];
#pragma unroll
      for (int ct = 0; ct < 4; ++ct) {
        s[ct] = (f32x4){0.f, 0.f, 0.f, 0.f};
        int krow = ct * 16 + lr;
#pragma unroll
        for (int ks = 0; ks < 4; ++ks) {
          short8 bf = *(const short8*)&Kc[krow * 128 + (((ks * 4 + kb) ^ (krow & 7)) * 8)];
          s[ct] = __builtin_amdgcn_mfma_f32_16x16x32_bf16(qf[ks], bf, s[ct], 0, 0, 0);
        }
      }
      const bool needmask = (kv0 + 63 > qw);
      float pe[4][4];
#pragma unroll
      for (int r = 0; r < 4; ++r) {
        const int qi = qw + kb * 4 + r;
        float mx = -3.0e4f;
#pragma unroll
        for (int ct = 0; ct < 4; ++ct) {
          float v = s[ct][r];
          if (needmask && (kv0 + ct * 16 + lr > qi)) v = -3.0e4f;
          s[ct][r] = v;
          mx = fmaxf(mx, v);
        }
        mx = fmaxf(mx, __shfl_xor(mx, 1));
        mx = fmaxf(mx, __shfl_xor(mx, 2));
        mx = fmaxf(mx, __shfl_xor(mx, 4));
        mx = fmaxf(mx, __shfl_xor(mx, 8));
        if (mx > mrow[r] + 8.f) {          // defer-max (T13), log2 units
          float alpha = EXP2F(mrow[r] - mx);
          mrow[r] = mx;
          lrow[r] *= alpha;
#pragma unroll
          for (int cc = 0; cc < 8; ++cc) ctx[cc][r] *= alpha;
        }
        float rs = 0.f;
#pragma unroll
        for (int ct = 0; ct < 4; ++ct) {
          float e = EXP2F(s[ct][r] - mrow[r]);
          pe[ct][r] = e;
          rs += e;
        }
        rs += __shfl_xor(rs, 1);
        rs += __shfl_xor(rs, 2);
        rs += __shfl_xor(rs, 4);
        rs += __shfl_xor(rs, 8);
        lrow[r] += rs;
      }
      // P -> per-wave LDS (swizzled)
#pragma unroll
      for (int ct = 0; ct < 4; ++ct)
#pragma unroll
        for (int r = 0; r < 4; ++r) {
          int prow = kb * 4 + r, pcol = ct * 16 + lr;
          Pb[w][prow * 64 + (pcol ^ ((prow & 7) * 8))] = f2bf(pe[ct][r]);
        }
      // PV: ctx[16 x 128] += P[16 x 64] * V[64 x 128]
      short8 pa[2];
#pragma unroll
      for (int ks = 0; ks < 2; ++ks)
        pa[ks] = *(const short8*)&Pb[w][lr * 64 + (((ks * 4 + kb) ^ (lr & 7)) * 8)];
#pragma unroll
      for (int cc = 0; cc < 8; ++cc) {
        int vrow = cc * 16 + lr;
#pragma unroll
        for (int ks = 0; ks < 2; ++ks) {
          short8 vb = *(const short8*)&Vc[vrow * 64 + (((ks * 4 + kb) ^ (vrow & 7)) * 8)];
          ctx[cc] = __builtin_amdgcn_mfma_f32_16x16x32_bf16(pa[ks], vb, ctx[cc], 0, 0, 0);
        }
      }
      __syncthreads();
      cbuf ^= 1;
    }
    // epilogue: ctx /= l, write bf16
#pragma unroll
    for (int r = 0; r < 4; ++r) {
      float inv = 1.f / lrow[r];
      size_t rowoff = (size_t)(b * SEQ + qw + kb * 4 + r) * DM + h * NHD;
#pragma unroll
      for (int cc = 0; cc < 8; ++cc)
        O[rowoff + cc * 16 + lr] = f2bf(ctx[cc][r] * inv);
    }
  }
}

// ---------------------------------------------------------------------------
extern "C" void kernel_launch(void* const* d_in, const int* in_sizes, int n_in,
                              void* d_out, int out_size, void* d_ws, size_t ws_size,
                              hipStream_t stream) {
  const float* X  = (const float*)d_in[0];
  const float* Wq = (const float*)d_in[1];
  const float* Wk = (const float*)d_in[2];
  const float* Wv = (const float*)d_in[3];
  const float* Wo = (const float*)d_in[4];
  const float* bo = (const float*)d_in[5];
  float* out = (float*)d_out;

  unsigned short* ws = (unsigned short*)d_ws;
  unsigned short* Xb  = ws;                    // 8388608
  unsigned short* Wqb = ws + 8388608;          // 4194304
  unsigned short* Wkb = ws + 12582912;
  unsigned short* Wvb = ws + 16777216;
  unsigned short* Wob = ws + 20971520;
  unsigned short* Qb  = ws + 25165824;         // 8388608
  unsigned short* Kb  = ws + 33554432;
  unsigned short* Vtb = ws + 41943040;         // Vt[(b*16+h)*128+d][s]
  unsigned short* Cb  = ws + 50331648;

  cast_bf16_k<<<4096, 256, 0, stream>>>(X, Xb, 1048576);
  cast_w4_k<<<8192, 256, 0, stream>>>(Wq, Wk, Wv, Wo, Wqb, Wkb, Wvb, Wob);

  gemm_qk_k<<<dim3(16, 32, 2), 256, 0, stream>>>(Xb, Wqb, Wkb, Qb, Kb);
  gemm_vt_k<<<dim3(32, 16), 256, 0, stream>>>(Wvb, Xb, Vtb);
  attn_k<<<512, 256, 0, stream>>>(Qb, Kb, Vtb, Cb);
  gemm_o_k<<<dim3(16, 32), 256, 0, stream>>>(Cb, Wob, bo, out);
}

// Round 5
// 291.862 us; speedup vs baseline: 1.9717x; 1.2696x over previous
//
#include <hip/hip_runtime.h>

// ---------------------------------------------------------------------------
// MultiHeadAttention: out = softmax_causal((XWq^T)(XWk^T)^T / sqrt(S)) (XWv^T) Wo^T + b
// B=2, S=2048, D=2048, H=16, HD=128.  All compute in bf16 MFMA, fp32 accum.
// Softmax runs in exp2 domain: Wq is pre-scaled by (1/sqrt(S))*log2(e).
// ---------------------------------------------------------------------------

typedef __attribute__((ext_vector_type(8))) short short8;
typedef __attribute__((ext_vector_type(4))) float f32x4;

#define SEQ 2048
#define DM  2048
#define NHD 128
#define QSCALE (0.022097086912079608f * 1.4426950408889634f)  // 1/sqrt(2048) * log2(e)

// raw v_exp_f32 (2^x) — avoids glibc __exp2f macro collision
#define EXP2F(x) __builtin_amdgcn_exp2f(x)

__device__ __forceinline__ unsigned short f2bf(float f) {
  unsigned u = __builtin_bit_cast(unsigned, f);
  u += 0x7FFFu + ((u >> 16) & 1u);          // RNE
  return (unsigned short)(u >> 16);
}

__device__ __forceinline__ void gll16(const void* g, void* l) {
  __builtin_amdgcn_global_load_lds((const __attribute__((address_space(1))) void*)g,
                                   (__attribute__((address_space(3))) void*)l, 16, 0, 0);
}

// ---- DPP 16-lane reductions (VALU pipe, no LDS crossbar) ------------------
// quad_perm xor1 = 0xB1, quad_perm xor2 = 0x4E, row_ror:4 = 0x124, row_ror:8 = 0x128
template <int CTRL>
__device__ __forceinline__ float dpp_mv(float x) {
  int xi = __builtin_bit_cast(int, x);
  return __builtin_bit_cast(float,
      __builtin_amdgcn_update_dpp(xi, xi, CTRL, 0xF, 0xF, false));
}
__device__ __forceinline__ float red16_max(float x) {
  x = fmaxf(x, dpp_mv<0xB1>(x));
  x = fmaxf(x, dpp_mv<0x4E>(x));
  x = fmaxf(x, dpp_mv<0x124>(x));
  x = fmaxf(x, dpp_mv<0x128>(x));
  return x;
}
__device__ __forceinline__ float red16_sum(float x) {
  x += dpp_mv<0xB1>(x);
  x += dpp_mv<0x4E>(x);
  x += dpp_mv<0x124>(x);
  x += dpp_mv<0x128>(x);
  return x;
}

// ---------------- cast fp32 -> bf16, 8 elems/thread ------------------------
__global__ __launch_bounds__(256) void cast_bf16_k(const float* __restrict__ in,
                                                   unsigned short* __restrict__ out,
                                                   int n8) {
  int i = blockIdx.x * 256 + threadIdx.x;
  if (i >= n8) return;
  const f32x4* p = (const f32x4*)in + (size_t)i * 2;
  f32x4 a = p[0], b = p[1];
  short8 o;
  o[0] = (short)f2bf(a[0]); o[1] = (short)f2bf(a[1]);
  o[2] = (short)f2bf(a[2]); o[3] = (short)f2bf(a[3]);
  o[4] = (short)f2bf(b[0]); o[5] = (short)f2bf(b[1]);
  o[6] = (short)f2bf(b[2]); o[7] = (short)f2bf(b[3]);
  *(short8*)(out + (size_t)i * 8) = o;
}

// fused cast of the 4 weight matrices; Wq gets QSCALE folded in.
__global__ __launch_bounds__(256) void cast_w4_k(const float* __restrict__ Wq,
                                                 const float* __restrict__ Wk,
                                                 const float* __restrict__ Wv,
                                                 const float* __restrict__ Wo,
                                                 unsigned short* __restrict__ Wqb,
                                                 unsigned short* __restrict__ Wkb,
                                                 unsigned short* __restrict__ Wvb,
                                                 unsigned short* __restrict__ Wob) {
  int i = blockIdx.x * 256 + threadIdx.x;     // 0 .. 4*524288-1
  int r = i >> 19, j = i & 524287;
  const float* src = (r == 0) ? Wq : (r == 1) ? Wk : (r == 2) ? Wv : Wo;
  unsigned short* dst = (r == 0) ? Wqb : (r == 1) ? Wkb : (r == 2) ? Wvb : Wob;
  float sc = (r == 0) ? QSCALE : 1.0f;
  const f32x4* p = (const f32x4*)src + (size_t)j * 2;
  f32x4 a = p[0], b = p[1];
  short8 o;
  o[0] = (short)f2bf(a[0] * sc); o[1] = (short)f2bf(a[1] * sc);
  o[2] = (short)f2bf(a[2] * sc); o[3] = (short)f2bf(a[3] * sc);
  o[4] = (short)f2bf(b[0] * sc); o[5] = (short)f2bf(b[1] * sc);
  o[6] = (short)f2bf(b[2] * sc); o[7] = (short)f2bf(b[3] * sc);
  *(short8*)(dst + (size_t)j * 8) = o;
}

// ---------------- m97-structure 128x128 bf16 GEMM core ---------------------
__device__ __forceinline__ void gemm_core(const unsigned short* __restrict__ A,
                                          const unsigned short* __restrict__ W,
                                          unsigned short* la, unsigned short* lb,
                                          f32x4 acc[4][4],
                                          int m0, int n0) {
  const int t = threadIdx.x, w = t >> 6, l = t & 63;
  const int lr = l & 15, kb = l >> 4;
  const int wm = w >> 1, wn = w & 1;
  const int i0 = w * 64 + l, i1 = 256 + w * 64 + l;     // granule ids (16B)
  for (int kt = 0; kt < DM / 32; ++kt) {
    const int k0 = kt * 32;
    gll16(A + (size_t)(m0 + (i0 >> 2)) * DM + k0 + (i0 & 3) * 8, &la[(size_t)w * 512]);
    gll16(A + (size_t)(m0 + (i1 >> 2)) * DM + k0 + (i1 & 3) * 8, &la[(size_t)(4 + w) * 512]);
    gll16(W + (size_t)(n0 + (i0 >> 2)) * DM + k0 + (i0 & 3) * 8, &lb[(size_t)w * 512]);
    gll16(W + (size_t)(n0 + (i1 >> 2)) * DM + k0 + (i1 & 3) * 8, &lb[(size_t)(4 + w) * 512]);
    __syncthreads();
    short8 af[4], bfr[4];
#pragma unroll
    for (int mi = 0; mi < 4; ++mi)
      af[mi] = *(const short8*)&la[(wm * 64 + mi * 16 + lr) * 32 + kb * 8];
#pragma unroll
    for (int ni = 0; ni < 4; ++ni)
      bfr[ni] = *(const short8*)&lb[(wn * 64 + ni * 16 + lr) * 32 + kb * 8];
#pragma unroll
    for (int mi = 0; mi < 4; ++mi)
#pragma unroll
      for (int ni = 0; ni < 4; ++ni)
        acc[mi][ni] = __builtin_amdgcn_mfma_f32_16x16x32_bf16(af[mi], bfr[ni], acc[mi][ni], 0, 0, 0);
    __syncthreads();
  }
}

// Q and K projections
__global__ __launch_bounds__(256) void gemm_qk_k(const unsigned short* __restrict__ X,
                                                 const unsigned short* __restrict__ Wq,
                                                 const unsigned short* __restrict__ Wk,
                                                 unsigned short* __restrict__ Qo,
                                                 unsigned short* __restrict__ Ko) {
  __shared__ unsigned short la[128 * 32];
  __shared__ unsigned short lb[128 * 32];
  const int z = blockIdx.z;
  const unsigned short* W = z ? Wk : Wq;
  unsigned short* Y = z ? Ko : Qo;
  const int m0 = blockIdx.y * 128, n0 = blockIdx.x * 128;
  const int t = threadIdx.x, w = t >> 6, l = t & 63;
  const int lr = l & 15, kb = l >> 4;
  const int wm = w >> 1, wn = w & 1;
  f32x4 acc[4][4] = {};
  gemm_core(X, W, la, lb, acc, m0, n0);
#pragma unroll
  for (int mi = 0; mi < 4; ++mi)
#pragma unroll
    for (int ni = 0; ni < 4; ++ni)
#pragma unroll
      for (int r = 0; r < 4; ++r) {
        int row = m0 + wm * 64 + mi * 16 + kb * 4 + r;
        int col = n0 + wn * 64 + ni * 16 + lr;
        Y[(size_t)row * DM + col] = f2bf(acc[mi][ni][r]);
      }
}

// V projection written transposed: Vt[(b*16+h)*128+d][s]
__global__ __launch_bounds__(256) void gemm_vt_k(const unsigned short* __restrict__ Wv,
                                                 const unsigned short* __restrict__ X,
                                                 unsigned short* __restrict__ Vt) {
  __shared__ unsigned short la[128 * 32];
  __shared__ unsigned short lb[128 * 32];
  const int m0 = blockIdx.y * 128, n0 = blockIdx.x * 128;
  const int t = threadIdx.x, w = t >> 6, l = t & 63;
  const int lr = l & 15, kb = l >> 4;
  const int wm = w >> 1, wn = w & 1;
  f32x4 acc[4][4] = {};
  gemm_core(Wv, X, la, lb, acc, m0, n0);
#pragma unroll
  for (int mi = 0; mi < 4; ++mi)
#pragma unroll
    for (int ni = 0; ni < 4; ++ni)
#pragma unroll
      for (int r = 0; r < 4; ++r) {
        int i = m0 + wm * 64 + mi * 16 + kb * 4 + r;   // h*128+d
        int j = n0 + wn * 64 + ni * 16 + lr;           // b*2048+s
        Vt[((size_t)(j >> 11) * 2048 + i) * 2048 + (j & 2047)] = f2bf(acc[mi][ni][r]);
      }
}

__global__ __launch_bounds__(256) void gemm_o_k(const unsigned short* __restrict__ A,
                                                const unsigned short* __restrict__ W,
                                                const float* __restrict__ bias,
                                                float* __restrict__ Y) {
  __shared__ unsigned short la[128 * 32];
  __shared__ unsigned short lb[128 * 32];
  const int m0 = blockIdx.y * 128, n0 = blockIdx.x * 128;
  const int t = threadIdx.x, w = t >> 6, l = t & 63;
  const int lr = l & 15, kb = l >> 4;
  const int wm = w >> 1, wn = w & 1;
  f32x4 acc[4][4] = {};
  gemm_core(A, W, la, lb, acc, m0, n0);
#pragma unroll
  for (int mi = 0; mi < 4; ++mi)
#pragma unroll
    for (int ni = 0; ni < 4; ++ni)
#pragma unroll
      for (int r = 0; r < 4; ++r) {
        int row = m0 + wm * 64 + mi * 16 + kb * 4 + r;
        int col = n0 + wn * 64 + ni * 16 + lr;
        Y[(size_t)row * DM + col] = acc[mi][ni][r] + bias[col];
      }
}

// ---------------- flash attention, causal, exp2-domain softmax -------------
// 1-D grid 512, XCD-swizzled: xcd=id&7 hosts bh in [xcd*4, xcd*4+4) so each
// XCD's L2 holds 4 bh x 1MB of K/V. Block does q-tiles {x, 31-x}: 33 k-tiles.
__device__ __forceinline__ void stage_tiles(const unsigned short* __restrict__ Kh,
                                            const unsigned short* __restrict__ Vh,
                                            unsigned short* KL, unsigned short* VL,
                                            int kv0, int t) {
#pragma unroll
  for (int c = 0; c < 4; ++c) {          // K: slot S = row*16 + (g^(row&7))
    int S = c * 256 + t;
    int row = S >> 4, g = (S & 15) ^ (row & 7);
    gll16(Kh + (size_t)(kv0 + row) * DM + g * 8, KL + (size_t)S * 8);
  }
#pragma unroll
  for (int c = 0; c < 4; ++c) {          // V: slot S = d*8 + (g^(d&7))
    int S = c * 256 + t;
    int d = S >> 3, g = (S & 7) ^ (d & 7);
    gll16(Vh + (size_t)d * SEQ + kv0 + g * 8, VL + (size_t)S * 8);
  }
}

__global__ __launch_bounds__(256) void attn_k(const unsigned short* __restrict__ Q,
                                              const unsigned short* __restrict__ K,
                                              const unsigned short* __restrict__ Vt,
                                              unsigned short* __restrict__ O) {
  __shared__ unsigned short KL[2][64 * 128];
  __shared__ unsigned short VL[2][128 * 64];
  __shared__ unsigned short Pb[4][16 * 64];
  const int t = threadIdx.x, w = t >> 6, l = t & 63;
  const int lr = l & 15, kb = l >> 4;
  const int id = blockIdx.x;
  const int xcd = id & 7, slot = id >> 3;
  const int bh = xcd * 4 + (slot & 3);          // T1: bh pinned to one XCD
  const int xpair = slot >> 2;                  // 0..15
  const int b = bh >> 4, h = bh & 15;
  const unsigned short* Kh = K + (size_t)b * SEQ * DM + h * NHD;
  const unsigned short* Vh = Vt + (size_t)bh * NHD * SEQ;

#pragma unroll 1
  for (int phase = 0; phase < 2; ++phase) {
    const int xq = phase ? (31 - xpair) : xpair;
    const int q0 = xq * 64;
    const int qw = q0 + w * 16;
    const int nkt = xq + 1;

    short8 qf[4];
    {
      const unsigned short* qp = Q + (size_t)(b * SEQ + qw + lr) * DM + h * NHD + kb * 8;
#pragma unroll
      for (int ks = 0; ks < 4; ++ks) qf[ks] = *(const short8*)(qp + ks * 32);
    }
    f32x4 ctx[8] = {};
    float mrow[4], lrow[4];
#pragma unroll
    for (int r = 0; r < 4; ++r) { mrow[r] = -3.0e4f; lrow[r] = 0.f; }

    stage_tiles(Kh, Vh, KL[0], VL[0], 0, t);
    __syncthreads();

    int cbuf = 0;
#pragma unroll 1
    for (int kt = 0; kt < nkt; ++kt) {
      const int kv0 = kt * 64;
      if (kt + 1 < nkt) stage_tiles(Kh, Vh, KL[cbuf ^ 1], VL[cbuf ^ 1], kv0 + 64, t);
      const unsigned short* Kc = KL[cbuf];
      const unsigned short* Vc = VL[cbuf];
      // QK^T: s[ct][r] = log2-domain scores[q=kb*4+r][key=ct*16+lr]
      f32x4 s[4];
#pragma unroll
      for (int ct = 0; ct < 4; ++ct) {
        s[ct] = (f32x4){0.f, 0.f, 0.f, 0.f};
        int krow = ct * 16 + lr;
#pragma unroll
        for (int ks = 0; ks < 4; ++ks) {
          short8 bf = *(const short8*)&Kc[krow * 128 + (((ks * 4 + kb) ^ (krow & 7)) * 8)];
          s[ct] = __builtin_amdgcn_mfma_f32_16x16x32_bf16(qf[ks], bf, s[ct], 0, 0, 0);
        }
      }
      const bool needmask = (kv0 + 63 > qw);
      float pe[4][4];
#pragma unroll
      for (int r = 0; r < 4; ++r) {
        const int qi = qw + kb * 4 + r;
        float mx = -3.0e4f;
#pragma unroll
        for (int ct = 0; ct < 4; ++ct) {
          float v = s[ct][r];
          if (needmask && (kv0 + ct * 16 + lr > qi)) v = -3.0e4f;
          s[ct][r] = v;
          mx = fmaxf(mx, v);
        }
        mx = red16_max(mx);                 // DPP, VALU-pipe (was 4x ds_bpermute)
        if (mx > mrow[r] + 8.f) {           // defer-max (T13), log2 units
          float alpha = EXP2F(mrow[r] - mx);
          mrow[r] = mx;
          lrow[r] *= alpha;
#pragma unroll
          for (int cc = 0; cc < 8; ++cc) ctx[cc][r] *= alpha;
        }
        float rs = 0.f;
#pragma unroll
        for (int ct = 0; ct < 4; ++ct) {
          float e = EXP2F(s[ct][r] - mrow[r]);
          pe[ct][r] = e;
          rs += e;
        }
        lrow[r] += red16_sum(rs);           // DPP, VALU-pipe
      }
      // P -> per-wave LDS (swizzled)
#pragma unroll
      for (int ct = 0; ct < 4; ++ct)
#pragma unroll
        for (int r = 0; r < 4; ++r) {
          int prow = kb * 4 + r, pcol = ct * 16 + lr;
          Pb[w][prow * 64 + (pcol ^ ((prow & 7) * 8))] = f2bf(pe[ct][r]);
        }
      // PV: ctx[16 x 128] += P[16 x 64] * V[64 x 128]
      short8 pa[2];
#pragma unroll
      for (int ks = 0; ks < 2; ++ks)
        pa[ks] = *(const short8*)&Pb[w][lr * 64 + (((ks * 4 + kb) ^ (lr & 7)) * 8)];
#pragma unroll
      for (int cc = 0; cc < 8; ++cc) {
        int vrow = cc * 16 + lr;
#pragma unroll
        for (int ks = 0; ks < 2; ++ks) {
          short8 vb = *(const short8*)&Vc[vrow * 64 + (((ks * 4 + kb) ^ (vrow & 7)) * 8)];
          ctx[cc] = __builtin_amdgcn_mfma_f32_16x16x32_bf16(pa[ks], vb, ctx[cc], 0, 0, 0);
        }
      }
      __syncthreads();
      cbuf ^= 1;
    }
    // epilogue: ctx /= l, write bf16
#pragma unroll
    for (int r = 0; r < 4; ++r) {
      float inv = 1.f / lrow[r];
      size_t rowoff = (size_t)(b * SEQ + qw + kb * 4 + r) * DM + h * NHD;
#pragma unroll
      for (int cc = 0; cc < 8; ++cc)
        O[rowoff + cc * 16 + lr] = f2bf(ctx[cc][r] * inv);
    }
  }
}

// ---------------------------------------------------------------------------
extern "C" void kernel_launch(void* const* d_in, const int* in_sizes, int n_in,
                              void* d_out, int out_size, void* d_ws, size_t ws_size,
                              hipStream_t stream) {
  const float* X  = (const float*)d_in[0];
  const float* Wq = (const float*)d_in[1];
  const float* Wk = (const float*)d_in[2];
  const float* Wv = (const float*)d_in[3];
  const float* Wo = (const float*)d_in[4];
  const float* bo = (const float*)d_in[5];
  float* out = (float*)d_out;

  unsigned short* ws = (unsigned short*)d_ws;
  unsigned short* Xb  = ws;                    // 8388608
  unsigned short* Wqb = ws + 8388608;          // 4194304
  unsigned short* Wkb = ws + 12582912;
  unsigned short* Wvb = ws + 16777216;
  unsigned short* Wob = ws + 20971520;
  unsigned short* Qb  = ws + 25165824;         // 8388608
  unsigned short* Kb  = ws + 33554432;
  unsigned short* Vtb = ws + 41943040;         // Vt[(b*16+h)*128+d][s]
  unsigned short* Cb  = ws + 50331648;

  cast_bf16_k<<<4096, 256, 0, stream>>>(X, Xb, 1048576);
  cast_w4_k<<<8192, 256, 0, stream>>>(Wq, Wk, Wv, Wo, Wqb, Wkb, Wvb, Wob);

  gemm_qk_k<<<dim3(16, 32, 2), 256, 0, stream>>>(Xb, Wqb, Wkb, Qb, Kb);
  gemm_vt_k<<<dim3(32, 16), 256, 0, stream>>>(Wvb, Xb, Vtb);
  attn_k<<<512, 256, 0, stream>>>(Qb, Kb, Vtb, Cb);
  gemm_o_k<<<dim3(16, 32), 256, 0, stream>>>(Cb, Wob, bo, out);
}